// Round 2
// baseline (97.083 us; speedup 1.0000x reference)
//
#include <hip/hip_runtime.h>

typedef float f4 __attribute__((ext_vector_type(4)));

#define LL 64
#define BB 2048
#define DD 512

__device__ __forceinline__ float fexp2(float x){ return __builtin_amdgcn_exp2f(x); }
__device__ __forceinline__ float frcpf_(float x){ return __builtin_amdgcn_rcpf(x); }
// sigmoid(z) = 1/(1+2^(-z*log2e))
__device__ __forceinline__ float fsigm(float z){ return frcpf_(1.0f + fexp2(-1.442695040888963f*z)); }
// tanh(z) = 1 - 2/(1+2^(z*2*log2e))
__device__ __forceinline__ float ftanh_(float z){ return 1.0f - 2.0f*frcpf_(1.0f + fexp2(2.885390081777927f*z)); }

__device__ __forceinline__ f4 ld4(const float* __restrict__ p){
  return *(const f4*)p;
}
// nontemporal: keep the 256MB x stream from evicting the L2-resident weights
__device__ __forceinline__ f4 ldnt4(const float* __restrict__ p){
  return __builtin_nontemporal_load((const f4*)p);
}

__global__ __launch_bounds__(128, 4) void rnn_fused_kernel(
    const float* __restrict__ x,
    const float* __restrict__ wxp, const float* __restrict__ wgp,
    const float* __restrict__ whp, const float* __restrict__ wup,
    const float* __restrict__ mp,  const float* __restrict__ fcw,
    const float* __restrict__ fcb, float* __restrict__ out)
{
  __shared__ float part[LL][33];   // [l][quad-group], +1 pad -> conflict-free
  const int tid = threadIdx.x;
  const int b   = blockIdx.x;
  const int d0  = tid << 2;        // 4 d's per thread, 128 threads cover D=512
  const int grp = tid >> 2;        // 32 quad-groups per block

  const f4 fw = ld4(fcw + d0);
  const float* xb_base = x + (size_t)b * DD + d0;
  const size_t PL = (size_t)BB * DD;   // plane stride

  // ---- t = 0: x_bar[0] = x[0]; h0 = tanh(x0*wx0); x_bar[1] = h0*wg0 + x0
  f4 x0  = ldnt4(xb_base);
  f4 w0x = ld4(wxp + d0);
  f4 w0g = ld4(wgp + d0);

  float c0 = x0[0]*fw[0] + x0[1]*fw[1] + x0[2]*fw[2] + x0[3]*fw[3];
  c0 += __shfl_xor(c0, 1);
  c0 += __shfl_xor(c0, 2);
  if ((tid & 3) == 0) part[0][grp] = c0;

  f4 h0v, h, xb;
  float c1 = 0.0f;
  #pragma unroll
  for (int j = 0; j < 4; ++j){
    h0v[j] = ftanh_(x0[j] * w0x[j]);
    xb[j]  = h0v[j] * w0g[j] + x0[j];
    c1    += xb[j] * fw[j];
  }
  h = h0v;
  c1 += __shfl_xor(c1, 1);
  c1 += __shfl_xor(c1, 2);
  if ((tid & 3) == 0) part[1][grp] = c1;

  // ---- prologue: x prefetch depth 2 (HBM stream), weights depth 1 (L2-hot)
  f4 xA = ldnt4(xb_base + 1 * PL);       // x[1]
  f4 xB = ldnt4(xb_base + 2 * PL);       // x[2]
  f4 wx = ld4(wxp + DD + d0);
  f4 wg = ld4(wgp + DD + d0);
  f4 wh = ld4(whp + DD + d0);
  f4 wu = ld4(wup + DD + d0);
  f4 mm = ld4(mp  + DD + d0);

  // ---- main scan: t = 1..62 (x[63]/w[63] are never used by the reference)
  #pragma unroll 1
  for (int t = 1; t < LL - 1; ++t){
    const int tn = (t < LL - 2) ? (t + 1) : (LL - 2);  // weights: distance 1
    const int tp = (t < LL - 3) ? (t + 2) : (LL - 2);  // x: distance 2
    f4 xC  = ldnt4(xb_base + (size_t)tp * PL);
    f4 wxn = ld4(wxp + tn * DD + d0);
    f4 wgn = ld4(wgp + tn * DD + d0);
    f4 whn = ld4(whp + tn * DD + d0);
    f4 wun = ld4(wup + tn * DD + d0);
    f4 mmn = ld4(mp  + tn * DD + d0);

    float cc = 0.0f;
    #pragma unroll
    for (int j = 0; j < 4; ++j){
      float xtr  = xb[j] + mm[j] * (xA[j] - xb[j]);    // x*m + xb*(1-m)
      float u    = ftanh_(xtr * wx[j]);
      float fpre = h[j] * wh[j] + u * wu[j];
      float f    = fsigm(fpre) * mm[j];
      float hn   = f * h[j] + fminf(1.0f - f, u);
      hn         = fmaxf(hn, h0v[j]);                  // h0 + relu(h-h0)
      h[j]  = hn;
      float nb = hn * wg[j] + xtr;                     // x_bar carry
      xb[j] = nb;
      cc += nb * fw[j];
    }
    cc += __shfl_xor(cc, 1);
    cc += __shfl_xor(cc, 2);
    if ((tid & 3) == 0) part[t + 1][grp] = cc;

    xA = xB; xB = xC;
    wx = wxn; wg = wgn; wh = whn; wu = wun; mm = mmn;
  }

  __syncthreads();

  // ---- epilogue: reduce 32 quad-partials per l, sigmoid, store
  if (tid < LL){
    float s = 0.0f;
    #pragma unroll
    for (int j = 0; j < 32; ++j) s += part[tid][j];
    out[(size_t)tid * BB + b] = fsigm(s + fcb[0]);
  }
}

extern "C" void kernel_launch(void* const* d_in, const int* in_sizes, int n_in,
                              void* d_out, int out_size, void* d_ws, size_t ws_size,
                              hipStream_t stream)
{
  const float* x   = (const float*)d_in[0];
  const float* wx  = (const float*)d_in[1];
  const float* wg  = (const float*)d_in[2];
  const float* wh  = (const float*)d_in[3];
  const float* wu  = (const float*)d_in[4];
  const float* m   = (const float*)d_in[5];
  const float* fcw = (const float*)d_in[6];
  const float* fcb = (const float*)d_in[7];
  float* out = (float*)d_out;
  rnn_fused_kernel<<<dim3(BB), dim3(128), 0, stream>>>(x, wx, wg, wh, wu, m, fcw, fcb, out);
}

// Round 3
// 67.274 us; speedup vs baseline: 1.4431x; 1.4431x over previous
//
#include <hip/hip_runtime.h>

typedef float f4 __attribute__((ext_vector_type(4)));
typedef float f2 __attribute__((ext_vector_type(2)));

#define LL 64
#define BB 2048
#define DD 512

__device__ __forceinline__ float fexp2(float x){ return __builtin_amdgcn_exp2f(x); }
__device__ __forceinline__ float frcpf_(float x){ return __builtin_amdgcn_rcpf(x); }
// sigmoid(z) = 1/(1+2^(-z*log2e))
__device__ __forceinline__ float fsigm(float z){ return frcpf_(1.0f + fexp2(-1.442695040888963f*z)); }
// tanh(z) = 1 - 2/(1+2^(z*2*log2e))
__device__ __forceinline__ float ftanh_(float z){ return 1.0f - 2.0f*frcpf_(1.0f + fexp2(2.885390081777927f*z)); }

__device__ __forceinline__ f4 ld4(const float* __restrict__ p){
  return *(const f4*)p;
}
__device__ __forceinline__ f4 vexp2(f4 v){
  f4 r; r[0]=fexp2(v[0]); r[1]=fexp2(v[1]); r[2]=fexp2(v[2]); r[3]=fexp2(v[3]); return r;
}
__device__ __forceinline__ f4 vrcp(f4 v){
  f4 r; r[0]=frcpf_(v[0]); r[1]=frcpf_(v[1]); r[2]=frcpf_(v[2]); r[3]=frcpf_(v[3]); return r;
}

__global__ __launch_bounds__(128, 3) void rnn_fused_kernel(
    const float* __restrict__ x,
    const float* __restrict__ wxp, const float* __restrict__ wgp,
    const float* __restrict__ whp, const float* __restrict__ wup,
    const float* __restrict__ mp,  const float* __restrict__ fcw,
    const float* __restrict__ fcb, float* __restrict__ out)
{
  __shared__ float part[LL][33];   // [l][quad-group], +1 pad -> conflict-free
  const int tid = threadIdx.x;
  const int b   = blockIdx.x;
  const int d0  = tid << 2;        // 4 d's per thread, 128 threads cover D=512
  const int grp = tid >> 2;        // 32 quad-groups per block

  const f4 fw = ld4(fcw + d0);
  const f2 fwlo = __builtin_shufflevector(fw, fw, 0, 1);
  const f2 fwhi = __builtin_shufflevector(fw, fw, 2, 3);
  const float* xb_base = x + (size_t)b * DD + d0;
  const size_t PL = (size_t)BB * DD;   // plane stride

  // ---- t = 0: x_bar[0] = x[0]; h0 = tanh(x0*wx0); x_bar[1] = h0*wg0 + x0
  f4 x0  = ld4(xb_base);
  f4 w0x = ld4(wxp + d0);
  f4 w0g = ld4(wgp + d0);

  float c0 = x0[0]*fw[0] + x0[1]*fw[1] + x0[2]*fw[2] + x0[3]*fw[3];
  c0 += __shfl_xor(c0, 1);
  c0 += __shfl_xor(c0, 2);
  if ((tid & 3) == 0) part[0][grp] = c0;

  f4 h0v, h, xb;
  float c1 = 0.0f;
  #pragma unroll
  for (int j = 0; j < 4; ++j){
    h0v[j] = ftanh_(x0[j] * w0x[j]);
    xb[j]  = h0v[j] * w0g[j] + x0[j];
    c1    += xb[j] * fw[j];
  }
  h = h0v;
  c1 += __shfl_xor(c1, 1);
  c1 += __shfl_xor(c1, 2);
  if ((tid & 3) == 0) part[1][grp] = c1;

  // ---- prologue: x prefetch depth 2 (HBM stream), weights depth 1 (L2-hot)
  f4 xA = ld4(xb_base + 1 * PL);       // x[1]
  f4 xB = ld4(xb_base + 2 * PL);       // x[2]
  f4 wx = ld4(wxp + DD + d0);
  f4 wg = ld4(wgp + DD + d0);
  f4 wh = ld4(whp + DD + d0);
  f4 wu = ld4(wup + DD + d0);
  f4 mm = ld4(mp  + DD + d0);

  // ---- main scan: t = 1..62 (x[63]/w[63] are never used by the reference)
  #pragma unroll 1
  for (int t = 1; t < LL - 1; ++t){
    const int tn = (t < LL - 2) ? (t + 1) : (LL - 2);  // weights: distance 1
    const int tp = (t < LL - 3) ? (t + 2) : (LL - 2);  // x: distance 2
    f4 xC  = ld4(xb_base + (size_t)tp * PL);
    f4 wxn = ld4(wxp + tn * DD + d0);
    f4 wgn = ld4(wgp + tn * DD + d0);
    f4 whn = ld4(whp + tn * DD + d0);
    f4 wun = ld4(wup + tn * DD + d0);
    f4 mmn = ld4(mp  + tn * DD + d0);

    // --- vectorized recurrence (packed fp32: v_pk_fma/add/mul) ---
    f4 xtr  = xb + mm * (xA - xb);                  // x*m + xb*(1-m)
    f4 targ = xtr * (wx * 2.885390081777927f);      // tanh arg * 2*log2e
    f4 u    = 1.0f - 2.0f * vrcp(1.0f + vexp2(targ));
    f4 sarg = -1.442695040888963f * (h * wh + u * wu);
    f4 ff   = vrcp(1.0f + vexp2(sarg)) * mm;        // f = sigmoid(.)*m
    f4 mn   = __builtin_elementwise_min(1.0f - ff, u);
    f4 hn   = ff * h + mn;
    hn      = __builtin_elementwise_max(hn, h0v);   // h0 + relu(h-h0)
    h  = hn;
    xb = hn * wg + xtr;                             // x_bar carry

    f2 c2 = __builtin_shufflevector(xb, xb, 0, 1) * fwlo
          + __builtin_shufflevector(xb, xb, 2, 3) * fwhi;
    float cc = c2[0] + c2[1];
    cc += __shfl_xor(cc, 1);
    cc += __shfl_xor(cc, 2);
    if ((tid & 3) == 0) part[t + 1][grp] = cc;

    xA = xB; xB = xC;
    wx = wxn; wg = wgn; wh = whn; wu = wun; mm = mmn;
  }

  __syncthreads();

  // ---- epilogue: reduce 32 quad-partials per l, sigmoid, store
  if (tid < LL){
    float s = 0.0f;
    #pragma unroll
    for (int j = 0; j < 32; ++j) s += part[tid][j];
    out[(size_t)tid * BB + b] = fsigm(s + fcb[0]);
  }
}

extern "C" void kernel_launch(void* const* d_in, const int* in_sizes, int n_in,
                              void* d_out, int out_size, void* d_ws, size_t ws_size,
                              hipStream_t stream)
{
  const float* x   = (const float*)d_in[0];
  const float* wx  = (const float*)d_in[1];
  const float* wg  = (const float*)d_in[2];
  const float* wh  = (const float*)d_in[3];
  const float* wu  = (const float*)d_in[4];
  const float* m   = (const float*)d_in[5];
  const float* fcw = (const float*)d_in[6];
  const float* fcb = (const float*)d_in[7];
  float* out = (float*)d_out;
  rnn_fused_kernel<<<dim3(BB), dim3(128), 0, stream>>>(x, wx, wg, wh, wu, m, fcw, fcb, out);
}

// Round 4
// 65.957 us; speedup vs baseline: 1.4719x; 1.0200x over previous
//
#include <hip/hip_runtime.h>

typedef float f4 __attribute__((ext_vector_type(4)));
typedef float f2 __attribute__((ext_vector_type(2)));

#define LL 64
#define BB 2048
#define DD 512
#define GB 2                 // batches per block (cross-batch weight reuse)
#define NBLK (BB / GB)       // 1024 blocks

__device__ __forceinline__ float fexp2(float x){ return __builtin_amdgcn_exp2f(x); }
__device__ __forceinline__ float frcpf_(float x){ return __builtin_amdgcn_rcpf(x); }
__device__ __forceinline__ float fsigm(float z){ return frcpf_(1.0f + fexp2(-1.442695040888963f*z)); }
__device__ __forceinline__ float ftanh_(float z){ return 1.0f - 2.0f*frcpf_(1.0f + fexp2(2.885390081777927f*z)); }

__device__ __forceinline__ f4 ld4(const float* __restrict__ p){
  return *(const f4*)p;
}
__device__ __forceinline__ f4 vexp2(f4 v){
  f4 r; r[0]=fexp2(v[0]); r[1]=fexp2(v[1]); r[2]=fexp2(v[2]); r[3]=fexp2(v[3]); return r;
}
__device__ __forceinline__ f4 vrcp(f4 v){
  f4 r; r[0]=frcpf_(v[0]); r[1]=frcpf_(v[1]); r[2]=frcpf_(v[2]); r[3]=frcpf_(v[3]); return r;
}

__global__ __launch_bounds__(128, 2) void rnn_fused_kernel(
    const float* __restrict__ x,
    const float* __restrict__ wxp, const float* __restrict__ wgp,
    const float* __restrict__ whp, const float* __restrict__ wup,
    const float* __restrict__ mp,  const float* __restrict__ fcw,
    const float* __restrict__ fcb, float* __restrict__ out)
{
  __shared__ float part[GB][LL][33];   // [g][l][quad-group], +1 pad
  const int tid = threadIdx.x;
  const int b0  = blockIdx.x;          // batch g adds g*NBLK
  const int d0  = tid << 2;
  const int grp = tid >> 2;

  const f4 fw = ld4(fcw + d0);
  const f2 fwlo = __builtin_shufflevector(fw, fw, 0, 1);
  const f2 fwhi = __builtin_shufflevector(fw, fw, 2, 3);
  const size_t PL = (size_t)BB * DD;

  const float* xbase[GB];
  #pragma unroll
  for (int g = 0; g < GB; ++g)
    xbase[g] = x + (size_t)(b0 + g * NBLK) * DD + d0;

  // ---- t = 0
  f4 w0x = ld4(wxp + d0);
  f4 w0g = ld4(wgp + d0);
  f4 h0v[GB], h[GB], xb[GB];
  #pragma unroll
  for (int g = 0; g < GB; ++g){
    f4 x0 = ld4(xbase[g]);
    float c0 = x0[0]*fw[0] + x0[1]*fw[1] + x0[2]*fw[2] + x0[3]*fw[3];
    c0 += __shfl_xor(c0, 1);
    c0 += __shfl_xor(c0, 2);
    if ((tid & 3) == 0) part[g][0][grp] = c0;

    float c1 = 0.0f;
    #pragma unroll
    for (int j = 0; j < 4; ++j){
      h0v[g][j] = ftanh_(x0[j] * w0x[j]);
      xb[g][j]  = h0v[g][j] * w0g[j] + x0[j];
      c1       += xb[g][j] * fw[j];
    }
    h[g] = h0v[g];
    c1 += __shfl_xor(c1, 1);
    c1 += __shfl_xor(c1, 2);
    if ((tid & 3) == 0) part[g][1][grp] = c1;
  }

  // ---- prologue: x depth-2 prefetch per batch; weights depth 1
  f4 xA[GB], xB[GB];
  #pragma unroll
  for (int g = 0; g < GB; ++g){
    xA[g] = ld4(xbase[g] + 1 * PL);
    xB[g] = ld4(xbase[g] + 2 * PL);
  }
  f4 wx = ld4(wxp + DD + d0);
  f4 wg = ld4(wgp + DD + d0);
  f4 wh = ld4(whp + DD + d0);
  f4 wu = ld4(wup + DD + d0);
  f4 mm = ld4(mp  + DD + d0);

  // ---- main scan: t = 1..62 (x[63]/w[63] never used)
  #pragma unroll 1
  for (int t = 1; t < LL - 1; ++t){
    const int tn = (t < LL - 2) ? (t + 1) : (LL - 2);  // weights dist 1
    const int tp = (t < LL - 3) ? (t + 2) : (LL - 2);  // x dist 2
    f4 xC[GB];
    #pragma unroll
    for (int g = 0; g < GB; ++g)
      xC[g] = ld4(xbase[g] + (size_t)tp * PL);
    f4 wxn = ld4(wxp + tn * DD + d0);
    f4 wgn = ld4(wgp + tn * DD + d0);
    f4 whn = ld4(whp + tn * DD + d0);
    f4 wun = ld4(wup + tn * DD + d0);
    f4 mmn = ld4(mp  + tn * DD + d0);

    // shared per-iter weight prescales (amortized over GB batches)
    f4 wxs = wx * 2.885390081777927f;
    f4 whs = wh * -1.442695040888963f;
    f4 wus = wu * -1.442695040888963f;

    #pragma unroll
    for (int g = 0; g < GB; ++g){
      f4 xtr  = xb[g] + mm * (xA[g] - xb[g]);
      f4 u    = 1.0f - 2.0f * vrcp(1.0f + vexp2(xtr * wxs));
      f4 sarg = h[g] * whs + u * wus;
      f4 ff   = vrcp(1.0f + vexp2(sarg)) * mm;
      f4 mn   = __builtin_elementwise_min(1.0f - ff, u);
      f4 hn   = ff * h[g] + mn;
      hn      = __builtin_elementwise_max(hn, h0v[g]);
      h[g]  = hn;
      xb[g] = hn * wg + xtr;

      f2 c2 = __builtin_shufflevector(xb[g], xb[g], 0, 1) * fwlo
            + __builtin_shufflevector(xb[g], xb[g], 2, 3) * fwhi;
      float cc = c2[0] + c2[1];
      cc += __shfl_xor(cc, 1);
      cc += __shfl_xor(cc, 2);
      if ((tid & 3) == 0) part[g][t + 1][grp] = cc;

      xA[g] = xB[g]; xB[g] = xC[g];
    }

    wx = wxn; wg = wgn; wh = whn; wu = wun; mm = mmn;
  }

  __syncthreads();

  // ---- epilogue: 128 threads = 2 batches x 64 l-rows
  {
    const int l = tid & 63;
    const int g = tid >> 6;
    float s = 0.0f;
    #pragma unroll
    for (int j = 0; j < 32; ++j) s += part[g][l][j];
    out[(size_t)l * BB + (b0 + g * NBLK)] = fsigm(s + fcb[0]);
  }
}

extern "C" void kernel_launch(void* const* d_in, const int* in_sizes, int n_in,
                              void* d_out, int out_size, void* d_ws, size_t ws_size,
                              hipStream_t stream)
{
  const float* x   = (const float*)d_in[0];
  const float* wx  = (const float*)d_in[1];
  const float* wg  = (const float*)d_in[2];
  const float* wh  = (const float*)d_in[3];
  const float* wu  = (const float*)d_in[4];
  const float* m   = (const float*)d_in[5];
  const float* fcw = (const float*)d_in[6];
  const float* fcb = (const float*)d_in[7];
  float* out = (float*)d_out;
  rnn_fused_kernel<<<dim3(NBLK), dim3(128), 0, stream>>>(x, wx, wg, wh, wu, m, fcw, fcb, out);
}

// Round 5
// 64.352 us; speedup vs baseline: 1.5086x; 1.0249x over previous
//
#include <hip/hip_runtime.h>

typedef float f4 __attribute__((ext_vector_type(4)));
typedef float f2 __attribute__((ext_vector_type(2)));

#define LL 64
#define BB 2048
#define DD 512
#define GB 2                 // batches per block (cross-batch weight reuse)
#define NBLK (BB / GB)       // 1024 blocks
#define XDEPTH 4             // x prefetch depth (HBM latency cover)

__device__ __forceinline__ float fexp2(float x){ return __builtin_amdgcn_exp2f(x); }
__device__ __forceinline__ float frcpf_(float x){ return __builtin_amdgcn_rcpf(x); }
__device__ __forceinline__ float fsigm(float z){ return frcpf_(1.0f + fexp2(-1.442695040888963f*z)); }
__device__ __forceinline__ float ftanh_(float z){ return 1.0f - 2.0f*frcpf_(1.0f + fexp2(2.885390081777927f*z)); }

__device__ __forceinline__ f4 ld4(const float* __restrict__ p){
  return *(const f4*)p;
}
__device__ __forceinline__ f4 vexp2(f4 v){
  f4 r; r[0]=fexp2(v[0]); r[1]=fexp2(v[1]); r[2]=fexp2(v[2]); r[3]=fexp2(v[3]); return r;
}
__device__ __forceinline__ f4 vrcp(f4 v){
  f4 r; r[0]=frcpf_(v[0]); r[1]=frcpf_(v[1]); r[2]=frcpf_(v[2]); r[3]=frcpf_(v[3]); return r;
}

__global__ __launch_bounds__(128, 2) void rnn_fused_kernel(
    const float* __restrict__ x,
    const float* __restrict__ wxp, const float* __restrict__ wgp,
    const float* __restrict__ whp, const float* __restrict__ wup,
    const float* __restrict__ mp,  const float* __restrict__ fcw,
    const float* __restrict__ fcb, float* __restrict__ out)
{
  __shared__ float part[GB][LL][33];   // [g][l][quad-group], +1 pad
  const int tid = threadIdx.x;
  const int b0  = blockIdx.x;          // batch g adds g*NBLK
  const int d0  = tid << 2;
  const int grp = tid >> 2;

  const f4 fw = ld4(fcw + d0);
  const f2 fwlo = __builtin_shufflevector(fw, fw, 0, 1);
  const f2 fwhi = __builtin_shufflevector(fw, fw, 2, 3);
  const size_t PL = (size_t)BB * DD;

  const float* xbase[GB];
  #pragma unroll
  for (int g = 0; g < GB; ++g)
    xbase[g] = x + (size_t)(b0 + g * NBLK) * DD + d0;

  // ---- deep x prefetch ring: x[1..4] per batch (issued first, before t=0 math)
  f4 xq[GB][XDEPTH];
  #pragma unroll
  for (int g = 0; g < GB; ++g)
    #pragma unroll
    for (int k = 0; k < XDEPTH; ++k)
      xq[g][k] = ld4(xbase[g] + (size_t)(1 + k) * PL);

  // ---- t = 0
  f4 w0x = ld4(wxp + d0);
  f4 w0g = ld4(wgp + d0);
  f4 h0v[GB], h[GB], xb[GB];
  #pragma unroll
  for (int g = 0; g < GB; ++g){
    f4 x0 = ld4(xbase[g]);
    float c0 = x0[0]*fw[0] + x0[1]*fw[1] + x0[2]*fw[2] + x0[3]*fw[3];
    c0 += __shfl_xor(c0, 1);
    c0 += __shfl_xor(c0, 2);
    if ((tid & 3) == 0) part[g][0][grp] = c0;

    float c1 = 0.0f;
    #pragma unroll
    for (int j = 0; j < 4; ++j){
      h0v[g][j] = ftanh_(x0[j] * w0x[j]);
      xb[g][j]  = h0v[g][j] * w0g[j] + x0[j];
      c1       += xb[g][j] * fw[j];
    }
    h[g] = h0v[g];
    c1 += __shfl_xor(c1, 1);
    c1 += __shfl_xor(c1, 2);
    if ((tid & 3) == 0) part[g][1][grp] = c1;
  }

  // ---- weights: distance-1 prefetch (L2-hot, short latency)
  f4 wx = ld4(wxp + DD + d0);
  f4 wg = ld4(wgp + DD + d0);
  f4 wh = ld4(whp + DD + d0);
  f4 wu = ld4(wup + DD + d0);
  f4 mm = ld4(mp  + DD + d0);

  // ---- main scan: t = 1..62 (x[63]/w[63] never used)
  #pragma unroll 1
  for (int t = 1; t < LL - 1; ++t){
    const int tn = (t < LL - 2) ? (t + 1) : (LL - 2);          // weights dist 1
    const int tp = (t + XDEPTH <= LL - 2) ? (t + XDEPTH) : (LL - 2);  // x dist XDEPTH
    f4 xC[GB];
    #pragma unroll
    for (int g = 0; g < GB; ++g)
      xC[g] = ld4(xbase[g] + (size_t)tp * PL);
    f4 wxn = ld4(wxp + tn * DD + d0);
    f4 wgn = ld4(wgp + tn * DD + d0);
    f4 whn = ld4(whp + tn * DD + d0);
    f4 wun = ld4(wup + tn * DD + d0);
    f4 mmn = ld4(mp  + tn * DD + d0);

    // shared per-iter weight prescales (amortized over GB batches)
    f4 wxs = wx * 2.885390081777927f;
    f4 whs = wh * -1.442695040888963f;
    f4 wus = wu * -1.442695040888963f;

    #pragma unroll
    for (int g = 0; g < GB; ++g){
      f4 xcur = xq[g][0];
      f4 xtr  = xb[g] + mm * (xcur - xb[g]);
      f4 u    = 1.0f - 2.0f * vrcp(1.0f + vexp2(xtr * wxs));
      f4 sarg = h[g] * whs + u * wus;
      f4 ff   = vrcp(1.0f + vexp2(sarg)) * mm;
      f4 mn   = __builtin_elementwise_min(1.0f - ff, u);
      f4 hn   = ff * h[g] + mn;
      hn      = __builtin_elementwise_max(hn, h0v[g]);
      h[g]  = hn;
      xb[g] = hn * wg + xtr;

      f2 c2 = __builtin_shufflevector(xb[g], xb[g], 0, 1) * fwlo
            + __builtin_shufflevector(xb[g], xb[g], 2, 3) * fwhi;
      float cc = c2[0] + c2[1];
      cc += __shfl_xor(cc, 1);
      cc += __shfl_xor(cc, 2);
      if ((tid & 3) == 0) part[g][t + 1][grp] = cc;

      // rotate the x ring (fully unrolled -> stays in registers)
      #pragma unroll
      for (int k = 0; k < XDEPTH - 1; ++k) xq[g][k] = xq[g][k + 1];
      xq[g][XDEPTH - 1] = xC[g];
    }

    wx = wxn; wg = wgn; wh = whn; wu = wun; mm = mmn;
  }

  __syncthreads();

  // ---- epilogue: 128 threads = 2 batches x 64 l-rows
  {
    const int l = tid & 63;
    const int g = tid >> 6;
    float s = 0.0f;
    #pragma unroll
    for (int j = 0; j < 32; ++j) s += part[g][l][j];
    out[(size_t)l * BB + (b0 + g * NBLK)] = fsigm(s + fcb[0]);
  }
}

extern "C" void kernel_launch(void* const* d_in, const int* in_sizes, int n_in,
                              void* d_out, int out_size, void* d_ws, size_t ws_size,
                              hipStream_t stream)
{
  const float* x   = (const float*)d_in[0];
  const float* wx  = (const float*)d_in[1];
  const float* wg  = (const float*)d_in[2];
  const float* wh  = (const float*)d_in[3];
  const float* wu  = (const float*)d_in[4];
  const float* m   = (const float*)d_in[5];
  const float* fcw = (const float*)d_in[6];
  const float* fcb = (const float*)d_in[7];
  float* out = (float*)d_out;
  rnn_fused_kernel<<<dim3(NBLK), dim3(128), 0, stream>>>(x, wx, wg, wh, wu, m, fcw, fcb, out);
}